// Round 9
// baseline (154.282 us; speedup 1.0000x reference)
//
#include <hip/hip_runtime.h>
#include <math.h>

#define NB 2
#define NL 2048
#define NK 32
#define NODE_F 128
#define EDGE_F 128

// output layout (float32 elements)
#define OFF_HV   0
#define OFF_HE   (NB*NL*NODE_F)                 // 524288
#define OFF_EIDX (OFF_HE + NB*NL*NK*EDGE_F)     // 17301504
#define OFF_X    (OFF_EIDX + NB*NL*NK)          // 17432576

#define ACH 8        // chunks (K=32) in half A  (k 0..255)
#define BCH 8        // chunks in half B         (k 256..511)
#define SAW 264      // sA row stride in shorts (528 B, 16B-aligned, bank-step 4 -> conflict-free)
#define NCH 16       // total chunks (K = 512)

typedef __attribute__((ext_vector_type(8))) short v8s;
typedef __attribute__((ext_vector_type(4))) float v4f;

__device__ __forceinline__ short f2bf(float f) {
    unsigned u = __float_as_uint(f);
    unsigned r = u + 0x7fffu + ((u >> 16) & 1u);
    return (short)(r >> 16);
}

#if __has_builtin(__builtin_amdgcn_exp2f)
#define EXP2F(x) __builtin_amdgcn_exp2f(x)
#else
#define EXP2F(x) __expf((x) * 0.6931471805599453f)
#endif

// pack top halves of two f32 bit-patterns (truncating f32->bf16) into one u32
__device__ __forceinline__ unsigned bfpack(float f0, float f1) {
    unsigned u0 = __float_as_uint(f0), u1 = __float_as_uint(f1);
#if __has_builtin(__builtin_amdgcn_perm)
    return __builtin_amdgcn_perm(u1, u0, 0x07060302u);  // {u1.hi16, u0.hi16}
#else
    return (u1 & 0xFFFF0000u) | (u0 >> 16);
#endif
}

// ---------------- DPP primitives (pure VALU, no LDS) ----------------
template<int CTRL>
__device__ __forceinline__ float dpp_add_f32(float x) {
    int p = __builtin_amdgcn_update_dpp(0, __float_as_int(x), CTRL, 0xF, 0xF, true);
    return x + __int_as_float(p);
}
template<int CTRL>
__device__ __forceinline__ float dpp_max_f32(float x) {
    int p = __builtin_amdgcn_update_dpp(0, __float_as_int(x), CTRL, 0xF, 0xF, true);
    return fmaxf(x, __int_as_float(p));
}
// 16-lane row sum: result in lane 15 of each row
__device__ __forceinline__ float dpp_row_sum16(float x) {
    x = dpp_add_f32<0x111>(x);   // row_shr:1
    x = dpp_add_f32<0x112>(x);   // row_shr:2
    x = dpp_add_f32<0x114>(x);   // row_shr:4
    x = dpp_add_f32<0x118>(x);   // row_shr:8
    return x;
}
// wave-wide sum: total lands in lane 63; broadcast via readlane
__device__ __forceinline__ float dpp_wave_sum(float x) {
    x = dpp_row_sum16(x);
    x = dpp_add_f32<0x142>(x);   // row_bcast15
    x = dpp_add_f32<0x143>(x);   // row_bcast31
    return __int_as_float(__builtin_amdgcn_readlane(__float_as_int(x), 63));
}
__device__ __forceinline__ float dpp_wave_max_nn(float x) {   // for x >= 0 (0-fill safe)
    x = dpp_max_f32<0x111>(x);
    x = dpp_max_f32<0x112>(x);
    x = dpp_max_f32<0x114>(x);
    x = dpp_max_f32<0x118>(x);
    x = dpp_max_f32<0x142>(x);
    x = dpp_max_f32<0x143>(x);
    return __int_as_float(__builtin_amdgcn_readlane(__float_as_int(x), 63));
}

// ---------------- DPP wave-min (u32) — lane 63 gets global min ----------------
template<int CTRL>
__device__ __forceinline__ unsigned dpp_min_u32_step(unsigned x) {
    unsigned p = (unsigned)__builtin_amdgcn_update_dpp((int)x, (int)x, CTRL, 0xF, 0xF, false);
    return p < x ? p : x;
}
__device__ __forceinline__ unsigned wave_min_u32_dpp(unsigned x) {
    x = dpp_min_u32_step<0xB1>(x);
    x = dpp_min_u32_step<0x4E>(x);
    x = dpp_min_u32_step<0x141>(x);
    x = dpp_min_u32_step<0x140>(x);
    x = dpp_min_u32_step<0x142>(x);
    x = dpp_min_u32_step<0x143>(x);
    return x;                         // lane 63 holds the global min
}

// ---------------- helpers ----------------
__device__ __forceinline__ void cross3(const float a[3], const float b[3], float c[3]) {
    c[0] = a[1]*b[2] - a[2]*b[1];
    c[1] = a[2]*b[0] - a[0]*b[2];
    c[2] = a[0]*b[1] - a[1]*b[0];
}
__device__ __forceinline__ float dot3(const float a[3], const float b[3]) {
    return a[0]*b[0] + a[1]*b[1] + a[2]*b[2];
}
__device__ float dihedral_f(const float p0[3], const float p1[3],
                            const float p2[3], const float p3[3]) {
    float u0[3], u1[3], u2[3];
    for (int d = 0; d < 3; d++) {
        u0[d] = p2[d] - p1[d];
        u1[d] = p0[d] - p1[d];
        u2[d] = p3[d] - p2[d];
    }
    float n1[3], n2[3], c12[3];
    cross3(u0, u1, n1);
    cross3(u0, u2, n2);
    cross3(u1, u2, c12);
    float l1 = sqrtf(dot3(n1, n1));
    float l2 = sqrtf(dot3(n2, n2));
    float cosang = dot3(n1, n2) / (l1 * l2);
    float s = dot3(c12, u0);
    float sgn = (s > 0.f) ? 1.f : ((s < 0.f) ? -1.f : 0.f);
    float r = sgn * acosf(cosang);
    return isnan(r) ? 0.f : r;
}

// ---------------- kernel 0: fused {knn_node 0..1023}{prep 1024..1039}{wconv 1040..1071} ----------------
// wconv B-rows by k: k<400 RBF We[65+k]; 400..402 We[465..467] (et/phi/psi); 403 be;
//                    404..468 We[k-404] (E_pos rows); else 0.
__global__ __launch_bounds__(256) void fused_pre_kernel(const float* __restrict__ X,
                                                        const float* __restrict__ mask,
                                                        const int* __restrict__ S,
                                                        const float* __restrict__ BB,
                                                        const float* __restrict__ SC,
                                                        const float* __restrict__ Wn,
                                                        const float* __restrict__ bn,
                                                        const float* __restrict__ gn,
                                                        const float* __restrict__ betan,
                                                        const float* __restrict__ We,
                                                        const float* __restrict__ be,
                                                        float* __restrict__ X5,
                                                        short* __restrict__ WTf,
                                                        int* __restrict__ EidxW,
                                                        float* __restrict__ out) {
    __shared__ float sCa[NL * 3];               // 24 KB : this block's batch Ca coords
    __shared__ unsigned long long sSel[4][64];  // 2 KB  : per-wave candidate slots
    int blk = blockIdx.x;
    int tid = threadIdx.x;

    if (blk >= 1024) {
        if (blk < 1040) {
            // ---- prep: X5 + X passthrough ----
            int row = (blk - 1024) * 256 + tid;
            float v[12];
#pragma unroll
            for (int t = 0; t < 12; t++) v[t] = X[row * 12 + t];
#pragma unroll
            for (int t = 0; t < 12; t++) out[OFF_X + row * 12 + t] = v[t];
            float bv[3], cv[3], cr[3];
            for (int d = 0; d < 3; d++) { bv[d] = v[3+d] - v[d]; cv[d] = v[6+d] - v[3+d]; }
            cross3(bv, cv, cr);
            float* x5 = X5 + row * 15;
#pragma unroll
            for (int t = 0; t < 12; t++) x5[t] = v[t];
            for (int d = 0; d < 3; d++)
                x5[12 + d] = -0.58273431f * cr[d] + 0.56802827f * bv[d] - 0.54067466f * cv[d] + v[3+d];
        } else {
            // ---- wconv ----
            int t = (blk - 1040) * 256 + tid;
            if (t >= NCH * 8 * 64) return;
            int lane = t & 63;
            int nt = (t >> 6) & 7;
            int ch = t >> 9;
            int n = nt * 16 + (lane & 15);
            int kbase = ch * 32 + (lane >> 4) * 8;
            short* dst = WTf + (size_t)t * 8;
#pragma unroll
            for (int j = 0; j < 8; j++) {
                int k = kbase + j;
                float f;
                if (k < 403) f = We[(65 + k) * 128 + n];       // RBF rows + et/phi/psi (465..467)
                else if (k == 403) f = be[n];
                else if (k <= 468) f = We[(k - 404) * 128 + n];// E_pos one-hot rows 0..64
                else f = 0.f;
                dst[j] = f2bf(f);
            }
        }
        return;
    }

    // ---- knn + node: 4 rows per block ----
    int w = tid >> 6, l = tid & 63;
    int row = blk * 4 + w;
    int b = row / NL;
    int base = b * NL;

    // stage this batch's Ca into LDS (once per block)
    for (int idx = tid; idx < NL; idx += 256) {
        const float* xp = X + (size_t)(base + idx) * 12 + 3;
        sCa[idx * 3 + 0] = xp[0];
        sCa[idx * 3 + 1] = xp[1];
        sCa[idx * 3 + 2] = xp[2];
    }

    // node features + LN (hides staging latency; independent of sCa)
    {
        int f0 = l, f1 = 64 + l;
        int s = S[row];
        float a0 = bn[f0] + Wn[s * NODE_F + f0];
        float a1 = bn[f1] + Wn[s * NODE_F + f1];
#pragma unroll
        for (int t = 0; t < 6; t++) {
            float x = BB[row * 6 + t];
            a0 += x * Wn[(21 + t) * NODE_F + f0];
            a1 += x * Wn[(21 + t) * NODE_F + f1];
        }
#pragma unroll
        for (int t = 0; t < 8; t++) {
            float x = SC[row * 8 + t];
            a0 += x * Wn[(27 + t) * NODE_F + f0];
            a1 += x * Wn[(27 + t) * NODE_F + f1];
        }
        float tot = dpp_wave_sum(a0 + a1);
        float mean = tot * (1.0f / 128.0f);
        float d0 = a0 - mean, d1 = a1 - mean;
        float qt = dpp_wave_sum(d0 * d0 + d1 * d1);
        float rstd = 1.0f / sqrtf(qt * (1.0f / 128.0f) + 1e-5f);
        out[OFF_HV + row * NODE_F + f0] = d0 * rstd * gn[f0] + betan[f0];
        out[OFF_HV + row * NODE_F + f1] = d1 * rstd * gn[f1] + betan[f1];
    }
    __syncthreads();

    const float* mrow = mask + base;
    int lrow = row - base;
    float cx = sCa[lrow * 3 + 0], cy = sCa[lrow * 3 + 1], cz = sCa[lrow * 3 + 2];
    float mi = mrow[lrow];

    // ---- adjusted distances (bit-identical selection semantics) ----
    float K[32];
    float lmax = 0.0f;
#pragma unroll
    for (int t = 0; t < 32; t++) {
        int j = t * 64 + l;
        float dx = __fsub_rn(cx, sCa[j * 3 + 0]);
        float dy = __fsub_rn(cy, sCa[j * 3 + 1]);
        float dz = __fsub_rn(cz, sCa[j * 3 + 2]);
        float ss = __fadd_rn(__fadd_rn(__fadd_rn(__fmul_rn(dx, dx), __fmul_rn(dy, dy)),
                                       __fmul_rn(dz, dz)), 1e-6f);
        float d = __fmul_rn(__fmul_rn(mi, mrow[j]), __fsqrt_rn(ss));
        K[t] = d;
        lmax = fmaxf(lmax, d);
    }
    lmax = dpp_wave_max_nn(lmax);
#pragma unroll
    for (int t = 0; t < 32; t++) {
        int j = t * 64 + l;
        float m2 = __fmul_rn(mi, mrow[j]);
        K[t] = __fadd_rn(K[t], __fmul_rn(__fmul_rn(2.0f, __fsub_rn(1.0f, m2)), lmax));
    }

    // ---- radix binary-search for tau: count(K <= tau) in [32, 64] ----
    unsigned lo_ = 0u, hi_ = 0x7f7fffffu, tau = 0x7f7fffffu;
#pragma unroll 1
    for (int it = 0; it < 31; it++) {
        unsigned mid = (lo_ + hi_) >> 1;
        float tf = __uint_as_float(mid);
        int c = 0;
#pragma unroll
        for (int t = 0; t < 32; t++) c += __popcll(__ballot(K[t] <= tf));
        if (c >= 32) {
            tau = mid;
            if (c <= 64) break;
            hi_ = mid - 1;
        } else {
            lo_ = mid + 1;
        }
    }
    float tauf = __uint_as_float(tau);

    // ---- compact candidates into slots (slot order == ascending j -> exact tie semantics) ----
    sSel[w][l] = ~0ull;
    int cbase = 0;
#pragma unroll
    for (int t = 0; t < 32; t++) {
        bool q = (K[t] <= tauf);
        unsigned long long m = __ballot(q);
        int pos = cbase + __popcll(m & ((1ull << l) - 1ull));
        if (q && pos < 64)
            sSel[w][pos] = (((unsigned long long)__float_as_uint(K[t])) << 32)
                           | (unsigned)(t * 64 + l);
        cbase += __popcll(m);
    }

    // ---- 32 extract-min rounds over 64 candidates (1 key/lane) ----
    unsigned long long key = sSel[w][l];
    int selj = 0;
#pragma unroll 1
    for (int r = 0; r < NK; r++) {
        unsigned hi = (unsigned)(key >> 32);
        unsigned gh = (unsigned)__builtin_amdgcn_readlane((int)wave_min_u32_dpp(hi), 63);
        unsigned long long mask_ = __ballot(hi == gh);
        int wl = __ffsll((unsigned long long)mask_) - 1;
        unsigned j = (unsigned)__builtin_amdgcn_readlane((int)(unsigned)key, wl);
        if (l == r) selj = (int)j;
        if (l == wl) key = ~0ull;
    }
    if (l < NK) {
        EidxW[row * NK + l] = selj;
        out[OFF_EIDX + row * NK + l] = (float)selj;
    }
}

// ---------------- kernel 1: edge10 — everything in the GEMM (K=512), pure-LN epilogue ----------------
__global__ __launch_bounds__(256, 4) void edge10_kernel(const float* __restrict__ X5,
                                                        const int* __restrict__ Eidx,
                                                        const int* __restrict__ chain,
                                                        const float* __restrict__ ge,
                                                        const float* __restrict__ betae,
                                                        const short* __restrict__ WTf,
                                                        float* __restrict__ out) {
    __shared__ short sA[64 * SAW];        // 33792 B : bf16 A-matrix, one K-half at a time
    __shared__ float sXj[64][17];         // 4352 B  : aliased by sRed in the epilogue
    __shared__ float sXi[2][15];          // 120 B
    __shared__ int   sJ[64];              // 256 B
    __shared__ int   sPos[64];            // 256 B
    __shared__ float sEt[64], sPhi[64], sPsi[64];   // 768 B   (total ~39.5 KB -> 4 blocks/CU)

    int tid = threadIdx.x;
    int e0 = blockIdx.x * 64;
    int b = e0 / (NL * NK);
    int i0 = (e0 / NK) % NL;
    int lane = tid & 63, w = tid >> 6;

    // ---- phase 0a: indices + Xi
    if (tid < 64) sJ[tid] = Eidx[e0 + tid];
    if (tid < 30) sXi[tid / 15][tid % 15] = X5[(b * NL + i0 + tid / 15) * 15 + (tid % 15)];
    __syncthreads();

    // ---- phase 0b: gather neighbor coords, pos/type
    for (int t = tid; t < 64 * 15; t += 256) {
        int e = t / 15, c2 = t % 15;
        sXj[e][c2] = X5[(b * NL + sJ[e]) * 15 + c2];
    }
    if (tid < 64) {
        int e = tid;
        int i = i0 + (e >> 5);
        int j = sJ[e];
        int off = j - i + 32;
        off = off < 0 ? 0 : (off > 64 ? 64 : off);
        sPos[e] = off;
        sEt[e] = (chain[b * NL + j] == chain[b * NL + i]) ? 2.0f : 1.0f;
    }
    __syncthreads();

    // ---- phase 0c: dihedrals on threads 0..127 (consumed in GEN_A(1), two barriers away)
    if (tid < 128) {
        int e = tid & 63;
        const float* xi = sXi[e >> 5];
        const float* xj = sXj[e];
        if (tid < 64) sPhi[e] = dihedral_f(&xi[6], &xj[0], &xj[3], &xj[6]);
        else          sPsi[e] = dihedral_f(&xi[0], &xi[3], &xi[6], &xj[0]);
    }

    // ---- A-matrix generator. k<400: RBF geometric recurrence. k>=400 (half 1 only):
    //      400 et, 401 phi, 402 psi, 403 1.0 (bias), 404+p one-hot at p==pos, else 0.
    const float Ac  = -0.92332482616893658f;
    const float K1c = 2.46219953645049755f;                 // -2*Ac*(4/3)
    const float Rc  = EXP2F(-1.64146635763366503f);         // 2^(Ac*(4/3)^2)
    const float R2c = Rc * Rc;
    int eg_ = w * 16 + (lane & 15);
    int q_ = lane >> 4;
    const float* xiG = sXi[eg_ >> 5];
    const float* xjG = sXj[eg_];
    short* rowp = sA + eg_ * SAW;
    float hfq = (float)(q_ & 1);              // o&1 == q&1 (o = q + 4t)
    int posG = sPos[eg_];

#define SPECV(k) ((k) == 400 ? sEt[eg_] : (k) == 401 ? sPhi[eg_] : (k) == 402 ? sPsi[eg_] : \
                  (k) == 403 ? 1.0f : (((k) - 404 == posG) ? 1.0f : 0.0f))

#define GEN_A(hh, CNT)                                                         \
    {                                                                          \
        _Pragma("unroll")                                                      \
        for (int t = 0; t < (CNT); t++) {                                      \
            int o = q_ + t * 4;                                                \
            int kg = (hh) * 256 + o * 8;                                       \
            union { unsigned u[4]; v8s v; } au;                                \
            if (kg >= 400) {                                                   \
                _Pragma("unroll")                                              \
                for (int jp = 0; jp < 4; jp++) {                               \
                    int k0 = kg + 2 * jp;                                      \
                    au.u[jp] = bfpack(SPECV(k0), SPECV(k0 + 1));               \
                }                                                              \
            } else {                                                           \
                int pair = kg >> 4;                                            \
                int a = pair / 5, cc = pair - a * 5;                           \
                float dx = xiG[a*3+0] - xjG[cc*3+0];                           \
                float dy = xiG[a*3+1] - xjG[cc*3+1];                           \
                float dz = xiG[a*3+2] - xjG[cc*3+2];                           \
                float d = sqrtf(dx*dx + dy*dy + dz*dz + 1e-6f);                \
                float ee = fminf(__fmaf_rn(hfq, -10.666666666666666f, d), 40.f); \
                float r0 = EXP2F(Ac * ee * ee);                                \
                float g  = EXP2F(K1c * ee) * Rc;                               \
                float r1 = r0 * g; g *= R2c;                                   \
                float r2 = r1 * g; g *= R2c;                                   \
                float r3 = r2 * g; g *= R2c;                                   \
                float r4 = r3 * g; g *= R2c;                                   \
                float r5 = r4 * g; g *= R2c;                                   \
                float r6 = r5 * g; g *= R2c;                                   \
                float r7 = r6 * g;                                             \
                au.u[0] = bfpack(r0, r1);                                      \
                au.u[1] = bfpack(r2, r3);                                      \
                au.u[2] = bfpack(r4, r5);                                      \
                au.u[3] = bfpack(r6, r7);                                      \
            }                                                                  \
            *(v8s*)(rowp + o * 8) = au.v;                                      \
        }                                                                      \
    }

    GEN_A(0, ACH)
    __syncthreads();

    // ---- MFMA: waves split N (2 nt tiles each); A from LDS, B from L2 (read once per block)
    int cl = lane & 15, kq = lane >> 4;
    int ntA = 2 * w, ntB = ntA + 1;
    const char* sAc = (const char*)sA;
    int abase0 = cl * (SAW * 2) + kq * 16;

    v4f acc[4][2];
#pragma unroll
    for (int eg = 0; eg < 4; eg++) { acc[eg][0] = (v4f){0.f,0.f,0.f,0.f}; acc[eg][1] = (v4f){0.f,0.f,0.f,0.f}; }

#define MMA_HALF(CHBASE, CNT)                                                  \
    {                                                                          \
        _Pragma("unroll 2")                                                    \
        for (int chl = 0; chl < (CNT); chl++) {                                \
            const v8s* gb = (const v8s*)WTf + ((size_t)((CHBASE) + chl) * 512 + lane); \
            v8s b0 = gb[ntA * 64];                                             \
            v8s b1 = gb[ntB * 64];                                             \
            int ab = abase0 + chl * 64;                                        \
            v8s a0 = *(const v8s*)(sAc + ab);                                  \
            v8s a1 = *(const v8s*)(sAc + ab + 16 * (SAW * 2));                 \
            v8s a2 = *(const v8s*)(sAc + ab + 32 * (SAW * 2));                 \
            v8s a3 = *(const v8s*)(sAc + ab + 48 * (SAW * 2));                 \
            acc[0][0] = __builtin_amdgcn_mfma_f32_16x16x32_bf16(a0, b0, acc[0][0], 0, 0, 0); \
            acc[0][1] = __builtin_amdgcn_mfma_f32_16x16x32_bf16(a0, b1, acc[0][1], 0, 0, 0); \
            acc[1][0] = __builtin_amdgcn_mfma_f32_16x16x32_bf16(a1, b0, acc[1][0], 0, 0, 0); \
            acc[1][1] = __builtin_amdgcn_mfma_f32_16x16x32_bf16(a1, b1, acc[1][1], 0, 0, 0); \
            acc[2][0] = __builtin_amdgcn_mfma_f32_16x16x32_bf16(a2, b0, acc[2][0], 0, 0, 0); \
            acc[2][1] = __builtin_amdgcn_mfma_f32_16x16x32_bf16(a2, b1, acc[2][1], 0, 0, 0); \
            acc[3][0] = __builtin_amdgcn_mfma_f32_16x16x32_bf16(a3, b0, acc[3][0], 0, 0, 0); \
            acc[3][1] = __builtin_amdgcn_mfma_f32_16x16x32_bf16(a3, b1, acc[3][1], 0, 0, 0); \
        }                                                                      \
    }

    MMA_HALF(0, ACH)
    __syncthreads();          // all waves done reading sA half A
    GEN_A(1, BCH)
    __syncthreads();
    MMA_HALF(ACH, BCH)

    // ---- epilogue: pure LN (DPP row sums; sRed aliases dead sXj)
    float2* sRed = (float2*)&sXj[0][0];   // [64 edges][4 waves]
    int nA = ntA * 16 + cl, nB = nA + 16;
    float r4A = ge[nA], r5A = betae[nA];
    float r4B = ge[nB], r5B = betae[nB];

#pragma unroll
    for (int eg = 0; eg < 4; eg++) {
#pragma unroll
        for (int r = 0; r < 4; r++) {
            int e = eg * 16 + kq * 4 + r;
            float v0 = acc[eg][0][r];
            float v1 = acc[eg][1][r];
            float s  = dpp_row_sum16(v0 + v1);
            float q2 = dpp_row_sum16(v0 * v0 + v1 * v1);
            if (cl == 15) sRed[e * 4 + w] = make_float2(s, q2);
        }
    }
    __syncthreads();

#pragma unroll
    for (int eg = 0; eg < 4; eg++) {
#pragma unroll
        for (int r = 0; r < 4; r++) {
            int e = eg * 16 + kq * 4 + r;
            float4 pa = *(const float4*)&sRed[e * 4];
            float4 pb = *(const float4*)&sRed[e * 4 + 2];
            float s  = pa.x + pa.z + pb.x + pb.z;
            float q2 = pa.y + pa.w + pb.y + pb.w;
            float mean = s * (1.0f / 128.0f);
            float var = q2 * (1.0f / 128.0f) - mean * mean;
            float rstd = rsqrtf(var + 1e-5f);
            size_t base = OFF_HE + (size_t)(e0 + e) * 128;
            out[base + nA] = (acc[eg][0][r] - mean) * rstd * r4A + r5A;
            out[base + nB] = (acc[eg][1][r] - mean) * rstd * r4B + r5B;
        }
    }
}

// ---------------- launch ----------------
extern "C" void kernel_launch(void* const* d_in, const int* in_sizes, int n_in,
                              void* d_out, int out_size, void* d_ws, size_t ws_size,
                              hipStream_t stream) {
    (void)in_sizes; (void)n_in; (void)out_size; (void)ws_size;
    const float* X    = (const float*)d_in[0];
    const int*   S    = (const int*)d_in[1];
    const float* BB   = (const float*)d_in[2];
    const float* SC   = (const float*)d_in[3];
    const int*   chain= (const int*)d_in[4];
    const float* mask = (const float*)d_in[5];
    const float* Wn   = (const float*)d_in[6];
    const float* bn   = (const float*)d_in[7];
    const float* gn   = (const float*)d_in[8];
    const float* betan= (const float*)d_in[9];
    const float* We   = (const float*)d_in[10];
    const float* be   = (const float*)d_in[11];
    const float* ge   = (const float*)d_in[12];
    const float* betae= (const float*)d_in[13];
    float* out = (float*)d_out;

    char* ws = (char*)d_ws;
    int*   EidxW = (int*)ws;                                  // 524288 B
    float* X5    = (float*)(ws + 524288);                     // 245760 B (ends 770048)
    short* WTf   = (short*)(ws + 770048);                     // 131072 B (ends 901120)

    hipLaunchKernelGGL(fused_pre_kernel, dim3(1024 + 16 + 32), dim3(256), 0, stream,
                       X, mask, S, BB, SC, Wn, bn, gn, betan, We, be,
                       X5, WTf, EidxW, out);
    hipLaunchKernelGGL(edge10_kernel, dim3(NB * NL * NK / 64), dim3(256), 0, stream,
                       X5, EidxW, chain, ge, betae, WTf, out);
}

// Round 10
// 152.183 us; speedup vs baseline: 1.0138x; 1.0138x over previous
//
#include <hip/hip_runtime.h>
#include <math.h>

#define NB 2
#define NL 2048
#define NK 32
#define NODE_F 128
#define EDGE_F 128

// output layout (float32 elements)
#define OFF_HV   0
#define OFF_HE   (NB*NL*NODE_F)                 // 524288
#define OFF_EIDX (OFF_HE + NB*NL*NK*EDGE_F)     // 17301504
#define OFF_X    (OFF_EIDX + NB*NL*NK)          // 17432576

#define ACH 8        // chunks (K=32) in half A  (k 0..255)
#define BCH 8        // chunks in half B         (k 256..511)
#define SAW 264      // sA row stride in shorts (528 B, 16B-aligned, bank-step 4)
#define NCH 16       // total chunks (K = 512)

typedef __attribute__((ext_vector_type(8))) short v8s;
typedef __attribute__((ext_vector_type(4))) float v4f;

__device__ __forceinline__ short f2bf(float f) {
    unsigned u = __float_as_uint(f);
    unsigned r = u + 0x7fffu + ((u >> 16) & 1u);
    return (short)(r >> 16);
}

#if __has_builtin(__builtin_amdgcn_exp2f)
#define EXP2F(x) __builtin_amdgcn_exp2f(x)
#else
#define EXP2F(x) __expf((x) * 0.6931471805599453f)
#endif

// pack top halves of two f32 bit-patterns (truncating f32->bf16) into one u32
__device__ __forceinline__ unsigned bfpack(float f0, float f1) {
    unsigned u0 = __float_as_uint(f0), u1 = __float_as_uint(f1);
#if __has_builtin(__builtin_amdgcn_perm)
    return __builtin_amdgcn_perm(u1, u0, 0x07060302u);  // {u1.hi16, u0.hi16}
#else
    return (u1 & 0xFFFF0000u) | (u0 >> 16);
#endif
}

// ---------------- DPP primitives (pure VALU, no LDS) ----------------
template<int CTRL>
__device__ __forceinline__ float dpp_add_f32(float x) {
    int p = __builtin_amdgcn_update_dpp(0, __float_as_int(x), CTRL, 0xF, 0xF, true);
    return x + __int_as_float(p);
}
template<int CTRL>
__device__ __forceinline__ float dpp_max_f32(float x) {
    int p = __builtin_amdgcn_update_dpp(0, __float_as_int(x), CTRL, 0xF, 0xF, true);
    return fmaxf(x, __int_as_float(p));
}
// 16-lane row sum: result in lane 15 of each row
__device__ __forceinline__ float dpp_row_sum16(float x) {
    x = dpp_add_f32<0x111>(x);   // row_shr:1
    x = dpp_add_f32<0x112>(x);   // row_shr:2
    x = dpp_add_f32<0x114>(x);   // row_shr:4
    x = dpp_add_f32<0x118>(x);   // row_shr:8
    return x;
}
// wave-wide sum: total lands in lane 63; broadcast via readlane
__device__ __forceinline__ float dpp_wave_sum(float x) {
    x = dpp_row_sum16(x);
    x = dpp_add_f32<0x142>(x);   // row_bcast15
    x = dpp_add_f32<0x143>(x);   // row_bcast31
    return __int_as_float(__builtin_amdgcn_readlane(__float_as_int(x), 63));
}
__device__ __forceinline__ float dpp_wave_max_nn(float x) {   // for x >= 0 (0-fill safe)
    x = dpp_max_f32<0x111>(x);
    x = dpp_max_f32<0x112>(x);
    x = dpp_max_f32<0x114>(x);
    x = dpp_max_f32<0x118>(x);
    x = dpp_max_f32<0x142>(x);
    x = dpp_max_f32<0x143>(x);
    return __int_as_float(__builtin_amdgcn_readlane(__float_as_int(x), 63));
}

// ---------------- lane-XOR exchange for bitonic sort ----------------
template<int J>
__device__ __forceinline__ unsigned long long lane_xor64(unsigned long long x) {
    if constexpr (J == 32) {
        return __shfl_xor(x, 32, 64);
    } else {
        unsigned lo = (unsigned)x, hi = (unsigned)(x >> 32);
        if constexpr (J == 1 || J == 2) {
            constexpr int ctrl = (J == 1) ? 0xB1 : 0x4E;   // quad_perm xor1 / xor2
            lo = (unsigned)__builtin_amdgcn_update_dpp((int)lo, (int)lo, ctrl, 0xF, 0xF, false);
            hi = (unsigned)__builtin_amdgcn_update_dpp((int)hi, (int)hi, ctrl, 0xF, 0xF, false);
        } else {
            constexpr int off = (J << 10) | 0x1F;          // ds_swizzle BitMode xor
            lo = (unsigned)__builtin_amdgcn_ds_swizzle((int)lo, off);
            hi = (unsigned)__builtin_amdgcn_ds_swizzle((int)hi, off);
        }
        return (((unsigned long long)hi) << 32) | lo;
    }
}

// ---------------- helpers ----------------
__device__ __forceinline__ void cross3(const float a[3], const float b[3], float c[3]) {
    c[0] = a[1]*b[2] - a[2]*b[1];
    c[1] = a[2]*b[0] - a[0]*b[2];
    c[2] = a[0]*b[1] - a[1]*b[0];
}
__device__ __forceinline__ float dot3(const float a[3], const float b[3]) {
    return a[0]*b[0] + a[1]*b[1] + a[2]*b[2];
}
__device__ float dihedral_f(const float p0[3], const float p1[3],
                            const float p2[3], const float p3[3]) {
    float u0[3], u1[3], u2[3];
    for (int d = 0; d < 3; d++) {
        u0[d] = p2[d] - p1[d];
        u1[d] = p0[d] - p1[d];
        u2[d] = p3[d] - p2[d];
    }
    float n1[3], n2[3], c12[3];
    cross3(u0, u1, n1);
    cross3(u0, u2, n2);
    cross3(u1, u2, c12);
    float l1 = sqrtf(dot3(n1, n1));
    float l2 = sqrtf(dot3(n2, n2));
    float cosang = dot3(n1, n2) / (l1 * l2);
    float s = dot3(c12, u0);
    float sgn = (s > 0.f) ? 1.f : ((s < 0.f) ? -1.f : 0.f);
    float r = sgn * acosf(cosang);
    return isnan(r) ? 0.f : r;
}

// ---------------- kernel 0: fused {knn_node 0..1023}{prep 1024..1039}{wconv 1040..1071} ----------------
// wconv B-rows by k: k<400 RBF We[65+k]; 400..402 We[465..467] (et/phi/psi); 403 be;
//                    404..468 We[k-404] (E_pos rows); else 0.
__global__ __launch_bounds__(256) void fused_pre_kernel(const float* __restrict__ X,
                                                        const float* __restrict__ mask,
                                                        const int* __restrict__ S,
                                                        const float* __restrict__ BB,
                                                        const float* __restrict__ SC,
                                                        const float* __restrict__ Wn,
                                                        const float* __restrict__ bn,
                                                        const float* __restrict__ gn,
                                                        const float* __restrict__ betan,
                                                        const float* __restrict__ We,
                                                        const float* __restrict__ be,
                                                        float* __restrict__ X5,
                                                        short* __restrict__ WTf,
                                                        int* __restrict__ EidxW,
                                                        float* __restrict__ out) {
    __shared__ float sCa[NL * 3];               // 24 KB : this block's batch Ca coords
    __shared__ unsigned long long sSel[4][64];  // 2 KB  : per-wave candidate slots
    int blk = blockIdx.x;
    int tid = threadIdx.x;

    if (blk >= 1024) {
        if (blk < 1040) {
            // ---- prep: X5 + X passthrough ----
            int row = (blk - 1024) * 256 + tid;
            float v[12];
#pragma unroll
            for (int t = 0; t < 12; t++) v[t] = X[row * 12 + t];
#pragma unroll
            for (int t = 0; t < 12; t++) out[OFF_X + row * 12 + t] = v[t];
            float bv[3], cv[3], cr[3];
            for (int d = 0; d < 3; d++) { bv[d] = v[3+d] - v[d]; cv[d] = v[6+d] - v[3+d]; }
            cross3(bv, cv, cr);
            float* x5 = X5 + row * 15;
#pragma unroll
            for (int t = 0; t < 12; t++) x5[t] = v[t];
            for (int d = 0; d < 3; d++)
                x5[12 + d] = -0.58273431f * cr[d] + 0.56802827f * bv[d] - 0.54067466f * cv[d] + v[3+d];
        } else {
            // ---- wconv ----
            int t = (blk - 1040) * 256 + tid;
            if (t >= NCH * 8 * 64) return;
            int lane = t & 63;
            int nt = (t >> 6) & 7;
            int ch = t >> 9;
            int n = nt * 16 + (lane & 15);
            int kbase = ch * 32 + (lane >> 4) * 8;
            short* dst = WTf + (size_t)t * 8;
#pragma unroll
            for (int j = 0; j < 8; j++) {
                int k = kbase + j;
                float f;
                if (k < 403) f = We[(65 + k) * 128 + n];       // RBF rows + et/phi/psi (465..467)
                else if (k == 403) f = be[n];
                else if (k <= 468) f = We[(k - 404) * 128 + n];// E_pos one-hot rows 0..64
                else f = 0.f;
                dst[j] = f2bf(f);
            }
        }
        return;
    }

    // ---- knn + node: 4 rows per block ----
    int w = tid >> 6, l = tid & 63;
    int row = blk * 4 + w;
    int b = row / NL;
    int base = b * NL;

    // stage this batch's Ca into LDS (once per block)
    for (int idx = tid; idx < NL; idx += 256) {
        const float* xp = X + (size_t)(base + idx) * 12 + 3;
        sCa[idx * 3 + 0] = xp[0];
        sCa[idx * 3 + 1] = xp[1];
        sCa[idx * 3 + 2] = xp[2];
    }

    // node features + LN (hides staging latency; independent of sCa)
    {
        int f0 = l, f1 = 64 + l;
        int s = S[row];
        float a0 = bn[f0] + Wn[s * NODE_F + f0];
        float a1 = bn[f1] + Wn[s * NODE_F + f1];
#pragma unroll
        for (int t = 0; t < 6; t++) {
            float x = BB[row * 6 + t];
            a0 += x * Wn[(21 + t) * NODE_F + f0];
            a1 += x * Wn[(21 + t) * NODE_F + f1];
        }
#pragma unroll
        for (int t = 0; t < 8; t++) {
            float x = SC[row * 8 + t];
            a0 += x * Wn[(27 + t) * NODE_F + f0];
            a1 += x * Wn[(27 + t) * NODE_F + f1];
        }
        float tot = dpp_wave_sum(a0 + a1);
        float mean = tot * (1.0f / 128.0f);
        float d0 = a0 - mean, d1 = a1 - mean;
        float qt = dpp_wave_sum(d0 * d0 + d1 * d1);
        float rstd = 1.0f / sqrtf(qt * (1.0f / 128.0f) + 1e-5f);
        out[OFF_HV + row * NODE_F + f0] = d0 * rstd * gn[f0] + betan[f0];
        out[OFF_HV + row * NODE_F + f1] = d1 * rstd * gn[f1] + betan[f1];
    }
    __syncthreads();

    const float* mrow = mask + base;
    int lrow = row - base;
    float cx = sCa[lrow * 3 + 0], cy = sCa[lrow * 3 + 1], cz = sCa[lrow * 3 + 2];
    float mi = mrow[lrow];

    // ---- adjusted distances (bit-identical selection semantics) ----
    float K[32];
    float lmax = 0.0f;
#pragma unroll
    for (int t = 0; t < 32; t++) {
        int j = t * 64 + l;
        float dx = __fsub_rn(cx, sCa[j * 3 + 0]);
        float dy = __fsub_rn(cy, sCa[j * 3 + 1]);
        float dz = __fsub_rn(cz, sCa[j * 3 + 2]);
        float ss = __fadd_rn(__fadd_rn(__fadd_rn(__fmul_rn(dx, dx), __fmul_rn(dy, dy)),
                                       __fmul_rn(dz, dz)), 1e-6f);
        float d = __fmul_rn(__fmul_rn(mi, mrow[j]), __fsqrt_rn(ss));
        K[t] = d;
        lmax = fmaxf(lmax, d);
    }
    lmax = dpp_wave_max_nn(lmax);
#pragma unroll
    for (int t = 0; t < 32; t++) {
        int j = t * 64 + l;
        float m2 = __fmul_rn(mi, mrow[j]);
        K[t] = __fadd_rn(K[t], __fmul_rn(__fmul_rn(2.0f, __fsub_rn(1.0f, m2)), lmax));
    }

    // ---- radix binary-search for tau: count(K <= tau) in [32, 64] ----
    unsigned lo_ = 0u, hi_ = 0x7f7fffffu, tau = 0x7f7fffffu;
#pragma unroll 1
    for (int it = 0; it < 31; it++) {
        unsigned mid = (lo_ + hi_) >> 1;
        float tf = __uint_as_float(mid);
        int c = 0;
#pragma unroll
        for (int t = 0; t < 32; t++) c += __popcll(__ballot(K[t] <= tf));
        if (c >= 32) {
            tau = mid;
            if (c <= 64) break;
            hi_ = mid - 1;
        } else {
            lo_ = mid + 1;
        }
    }
    float tauf = __uint_as_float(tau);

    // ---- compact candidates into slots (slot order == ascending j -> exact tie semantics) ----
    sSel[w][l] = ~0ull;
    int cbase = 0;
#pragma unroll
    for (int t = 0; t < 32; t++) {
        bool q = (K[t] <= tauf);
        unsigned long long m = __ballot(q);
        int pos = cbase + __popcll(m & ((1ull << l) - 1ull));
        if (q && pos < 64)
            sSel[w][pos] = (((unsigned long long)__float_as_uint(K[t])) << 32)
                           | (unsigned)(t * 64 + l);
        cbase += __popcll(m);
    }

    // ---- full bitonic sort of 64 u64 keys (unique keys -> == iterated extract-min) ----
    unsigned long long key = sSel[w][l];
#define BSTAGE(K_, J_) {                                                       \
    unsigned long long o_ = lane_xor64<J_>(key);                               \
    bool keepMin = (((l & (K_)) == 0) == ((l & (J_)) == 0));                   \
    unsigned long long mn_ = key < o_ ? key : o_;                              \
    key = keepMin ? mn_ : (key ^ o_ ^ mn_);                                    \
}
    BSTAGE(2, 1)
    BSTAGE(4, 2)  BSTAGE(4, 1)
    BSTAGE(8, 4)  BSTAGE(8, 2)  BSTAGE(8, 1)
    BSTAGE(16, 8) BSTAGE(16, 4) BSTAGE(16, 2) BSTAGE(16, 1)
    BSTAGE(32, 16) BSTAGE(32, 8) BSTAGE(32, 4) BSTAGE(32, 2) BSTAGE(32, 1)
    BSTAGE(64, 32) BSTAGE(64, 16) BSTAGE(64, 8) BSTAGE(64, 4) BSTAGE(64, 2) BSTAGE(64, 1)

    // lane r now holds the r-th smallest key
    if (l < NK) {
        int selj = (int)(unsigned)key;
        EidxW[row * NK + l] = selj;
        out[OFF_EIDX + row * NK + l] = (float)selj;
    }
}

// ---------------- kernel 1: edge11 — K=512 GEMM, pair-level RBF recurrence (2 exp / 16 values) ----------------
__global__ __launch_bounds__(256, 4) void edge11_kernel(const float* __restrict__ X5,
                                                        const int* __restrict__ Eidx,
                                                        const int* __restrict__ chain,
                                                        const float* __restrict__ ge,
                                                        const float* __restrict__ betae,
                                                        const short* __restrict__ WTf,
                                                        float* __restrict__ out) {
    __shared__ short sA[64 * SAW];        // 33792 B : bf16 A-matrix, one K-half at a time
    __shared__ float sXj[64][17];         // 4352 B  : aliased by sRed in the epilogue
    __shared__ float sXi[2][15];          // 120 B
    __shared__ int   sJ[64];              // 256 B
    __shared__ int   sPos[64];            // 256 B
    __shared__ float sEt[64], sPhi[64], sPsi[64];   // 768 B

    int tid = threadIdx.x;
    int e0 = blockIdx.x * 64;
    int b = e0 / (NL * NK);
    int i0 = (e0 / NK) % NL;
    int lane = tid & 63, w = tid >> 6;

    // ---- phase 0a: indices + Xi
    if (tid < 64) sJ[tid] = Eidx[e0 + tid];
    if (tid < 30) sXi[tid / 15][tid % 15] = X5[(b * NL + i0 + tid / 15) * 15 + (tid % 15)];
    __syncthreads();

    // ---- phase 0b: gather neighbor coords, pos/type
    for (int t = tid; t < 64 * 15; t += 256) {
        int e = t / 15, c2 = t % 15;
        sXj[e][c2] = X5[(b * NL + sJ[e]) * 15 + c2];
    }
    if (tid < 64) {
        int e = tid;
        int i = i0 + (e >> 5);
        int j = sJ[e];
        int off = j - i + 32;
        off = off < 0 ? 0 : (off > 64 ? 64 : off);
        sPos[e] = off;
        sEt[e] = (chain[b * NL + j] == chain[b * NL + i]) ? 2.0f : 1.0f;
    }
    __syncthreads();

    // ---- phase 0c: dihedrals on threads 0..127 (consumed in GEN_A(1), two barriers away)
    if (tid < 128) {
        int e = tid & 63;
        const float* xi = sXi[e >> 5];
        const float* xj = sXj[e];
        if (tid < 64) sPhi[e] = dihedral_f(&xi[6], &xj[0], &xj[3], &xj[6]);
        else          sPsi[e] = dihedral_f(&xi[0], &xi[3], &xi[6], &xj[0]);
    }

    // ---- A-matrix generator. One PAIR (16 k-slots) per (thread, t):
    //   RBF pairs p<25: v_m = exp2(Ac*(ee-m*D)^2), m=0..15, via geometric recurrence (2 exp).
    //   Specials p>=25 (half 1): 400 et, 401 phi, 402 psi, 403 1.0, 404+posG one-hot, else 0.
    const float Ac  = -0.92332482616893658f;
    const float K1c = 2.46219953645049755f;                 // -2*Ac*(4/3)
    const float Rc  = EXP2F(-1.64146635763366503f);         // 2^(Ac*(4/3)^2)
    const float R2c = Rc * Rc;
    int eg_ = w * 16 + (lane & 15);
    int q_ = lane >> 4;
    const float* xiG = sXi[eg_ >> 5];
    const float* xjG = sXj[eg_];
    short* rowp = sA + eg_ * SAW;
    int posG = sPos[eg_];

#define SPECV(k) ((k) == 400 ? sEt[eg_] : (k) == 401 ? sPhi[eg_] : (k) == 402 ? sPsi[eg_] : \
                  (k) == 403 ? 1.0f : (((k) - 404 == posG) ? 1.0f : 0.0f))

#define GEN_A(hh)                                                              \
    {                                                                          \
        _Pragma("unroll")                                                      \
        for (int t = 0; t < 4; t++) {                                          \
            int pl = q_ + t * 4;               /* pair-local 0..15 */          \
            int p  = (hh) * 16 + pl;           /* global pair */               \
            union { unsigned u[8]; v8s v[2]; } au;                             \
            if ((hh) == 1 && p >= 25) {                                        \
                _Pragma("unroll")                                              \
                for (int jp = 0; jp < 8; jp++) {                               \
                    int k0 = p * 16 + 2 * jp;                                  \
                    au.u[jp] = bfpack(SPECV(k0), SPECV(k0 + 1));               \
                }                                                              \
            } else {                                                           \
                int a = p / 5, cc = p - a * 5;                                 \
                float dx = xiG[a*3+0] - xjG[cc*3+0];                           \
                float dy = xiG[a*3+1] - xjG[cc*3+1];                           \
                float dz = xiG[a*3+2] - xjG[cc*3+2];                           \
                float d = sqrtf(dx*dx + dy*dy + dz*dz + 1e-6f);                \
                float ee = fminf(d, 40.f);                                     \
                float r0 = EXP2F(Ac * ee * ee);                                \
                float g  = EXP2F(K1c * ee) * Rc;                               \
                float r1  = r0  * g; g *= R2c;                                 \
                float r2  = r1  * g; g *= R2c;                                 \
                float r3  = r2  * g; g *= R2c;                                 \
                float r4  = r3  * g; g *= R2c;                                 \
                float r5  = r4  * g; g *= R2c;                                 \
                float r6  = r5  * g; g *= R2c;                                 \
                float r7  = r6  * g; g *= R2c;                                 \
                float r8  = r7  * g; g *= R2c;                                 \
                float r9  = r8  * g; g *= R2c;                                 \
                float r10 = r9  * g; g *= R2c;                                 \
                float r11 = r10 * g; g *= R2c;                                 \
                float r12 = r11 * g; g *= R2c;                                 \
                float r13 = r12 * g; g *= R2c;                                 \
                float r14 = r13 * g; g *= R2c;                                 \
                float r15 = r14 * g;                                           \
                au.u[0] = bfpack(r0,  r1);                                     \
                au.u[1] = bfpack(r2,  r3);                                     \
                au.u[2] = bfpack(r4,  r5);                                     \
                au.u[3] = bfpack(r6,  r7);                                     \
                au.u[4] = bfpack(r8,  r9);                                     \
                au.u[5] = bfpack(r10, r11);                                    \
                au.u[6] = bfpack(r12, r13);                                    \
                au.u[7] = bfpack(r14, r15);                                    \
            }                                                                  \
            *(v8s*)(rowp + pl * 16)     = au.v[0];                             \
            *(v8s*)(rowp + pl * 16 + 8) = au.v[1];                             \
        }                                                                      \
    }

    GEN_A(0)
    __syncthreads();

    // ---- MFMA: waves split N (2 nt tiles each); A from LDS, B from L2 (read once per block)
    int cl = lane & 15, kq = lane >> 4;
    int ntA = 2 * w, ntB = ntA + 1;
    const char* sAc = (const char*)sA;
    int abase0 = cl * (SAW * 2) + kq * 16;

    v4f acc[4][2];
#pragma unroll
    for (int eg = 0; eg < 4; eg++) { acc[eg][0] = (v4f){0.f,0.f,0.f,0.f}; acc[eg][1] = (v4f){0.f,0.f,0.f,0.f}; }

#define MMA_HALF(CHBASE, CNT)                                                  \
    {                                                                          \
        _Pragma("unroll 2")                                                    \
        for (int chl = 0; chl < (CNT); chl++) {                                \
            const v8s* gb = (const v8s*)WTf + ((size_t)((CHBASE) + chl) * 512 + lane); \
            v8s b0 = gb[ntA * 64];                                             \
            v8s b1 = gb[ntB * 64];                                             \
            int ab = abase0 + chl * 64;                                        \
            v8s a0 = *(const v8s*)(sAc + ab);                                  \
            v8s a1 = *(const v8s*)(sAc + ab + 16 * (SAW * 2));                 \
            v8s a2 = *(const v8s*)(sAc + ab + 32 * (SAW * 2));                 \
            v8s a3 = *(const v8s*)(sAc + ab + 48 * (SAW * 2));                 \
            acc[0][0] = __builtin_amdgcn_mfma_f32_16x16x32_bf16(a0, b0, acc[0][0], 0, 0, 0); \
            acc[0][1] = __builtin_amdgcn_mfma_f32_16x16x32_bf16(a0, b1, acc[0][1], 0, 0, 0); \
            acc[1][0] = __builtin_amdgcn_mfma_f32_16x16x32_bf16(a1, b0, acc[1][0], 0, 0, 0); \
            acc[1][1] = __builtin_amdgcn_mfma_f32_16x16x32_bf16(a1, b1, acc[1][1], 0, 0, 0); \
            acc[2][0] = __builtin_amdgcn_mfma_f32_16x16x32_bf16(a2, b0, acc[2][0], 0, 0, 0); \
            acc[2][1] = __builtin_amdgcn_mfma_f32_16x16x32_bf16(a2, b1, acc[2][1], 0, 0, 0); \
            acc[3][0] = __builtin_amdgcn_mfma_f32_16x16x32_bf16(a3, b0, acc[3][0], 0, 0, 0); \
            acc[3][1] = __builtin_amdgcn_mfma_f32_16x16x32_bf16(a3, b1, acc[3][1], 0, 0, 0); \
        }                                                                      \
    }

    MMA_HALF(0, ACH)
    __syncthreads();          // all waves done reading sA half A
    GEN_A(1)
    __syncthreads();
    MMA_HALF(ACH, BCH)

    // ---- epilogue: pure LN (DPP row sums; sRed aliases dead sXj)
    float2* sRed = (float2*)&sXj[0][0];   // [64 edges][4 waves]
    int nA = ntA * 16 + cl, nB = nA + 16;
    float r4A = ge[nA], r5A = betae[nA];
    float r4B = ge[nB], r5B = betae[nB];

#pragma unroll
    for (int eg = 0; eg < 4; eg++) {
#pragma unroll
        for (int r = 0; r < 4; r++) {
            int e = eg * 16 + kq * 4 + r;
            float v0 = acc[eg][0][r];
            float v1 = acc[eg][1][r];
            float s  = dpp_row_sum16(v0 + v1);
            float q2 = dpp_row_sum16(v0 * v0 + v1 * v1);
            if (cl == 15) sRed[e * 4 + w] = make_float2(s, q2);
        }
    }
    __syncthreads();

#pragma unroll
    for (int eg = 0; eg < 4; eg++) {
#pragma unroll
        for (int r = 0; r < 4; r++) {
            int e = eg * 16 + kq * 4 + r;
            float4 pa = *(const float4*)&sRed[e * 4];
            float4 pb = *(const float4*)&sRed[e * 4 + 2];
            float s  = pa.x + pa.z + pb.x + pb.z;
            float q2 = pa.y + pa.w + pb.y + pb.w;
            float mean = s * (1.0f / 128.0f);
            float var = q2 * (1.0f / 128.0f) - mean * mean;
            float rstd = rsqrtf(var + 1e-5f);
            size_t base = OFF_HE + (size_t)(e0 + e) * 128;
            out[base + nA] = (acc[eg][0][r] - mean) * rstd * r4A + r5A;
            out[base + nB] = (acc[eg][1][r] - mean) * rstd * r4B + r5B;
        }
    }
}

// ---------------- launch ----------------
extern "C" void kernel_launch(void* const* d_in, const int* in_sizes, int n_in,
                              void* d_out, int out_size, void* d_ws, size_t ws_size,
                              hipStream_t stream) {
    (void)in_sizes; (void)n_in; (void)out_size; (void)ws_size;
    const float* X    = (const float*)d_in[0];
    const int*   S    = (const int*)d_in[1];
    const float* BB   = (const float*)d_in[2];
    const float* SC   = (const float*)d_in[3];
    const int*   chain= (const int*)d_in[4];
    const float* mask = (const float*)d_in[5];
    const float* Wn   = (const float*)d_in[6];
    const float* bn   = (const float*)d_in[7];
    const float* gn   = (const float*)d_in[8];
    const float* betan= (const float*)d_in[9];
    const float* We   = (const float*)d_in[10];
    const float* be   = (const float*)d_in[11];
    const float* ge   = (const float*)d_in[12];
    const float* betae= (const float*)d_in[13];
    float* out = (float*)d_out;

    char* ws = (char*)d_ws;
    int*   EidxW = (int*)ws;                                  // 524288 B
    float* X5    = (float*)(ws + 524288);                     // 245760 B (ends 770048)
    short* WTf   = (short*)(ws + 770048);                     // 131072 B (ends 901120)

    hipLaunchKernelGGL(fused_pre_kernel, dim3(1024 + 16 + 32), dim3(256), 0, stream,
                       X, mask, S, BB, SC, Wn, bn, gn, betan, We, be,
                       X5, WTf, EidxW, out);
    hipLaunchKernelGGL(edge11_kernel, dim3(NB * NL * NK / 64), dim3(256), 0, stream,
                       X5, EidxW, chain, ge, betae, WTf, out);
}